// Round 15
// baseline (37061.923 us; speedup 1.0000x reference)
//
#include <hip/hip_runtime.h>
#include <math.h>

#define T_STEPS 4096
#define EMB 1024
#define HID 2048
#define CAT 1040
#define TAG 16
#define NBLK 256
#define NTHR 1024

// output offsets (floats)
#define OUT_LOGP 0
#define OUT_PROB (T_STEPS * TAG)
#define OUT_PRED (2 * T_STEPS * TAG)

__device__ __forceinline__ float sigf(float x) { return 1.0f / (1.0f + expf(-x)); }

// epoch-stamped 64-bit payload: [epoch:32 | payload:32]; value+freshness one
// atom. Relaxed agent-scope -> coherent point; no fences anywhere.
__device__ __forceinline__ unsigned long long aload64(const unsigned long long* p) {
  return __hip_atomic_load(p, __ATOMIC_RELAXED, __HIP_MEMORY_SCOPE_AGENT);
}
__device__ __forceinline__ void astore64(unsigned long long* p, unsigned long long v) {
  __hip_atomic_store(p, v, __ATOMIC_RELAXED, __HIP_MEMORY_SCOPE_AGENT);
}
__device__ __forceinline__ unsigned long long pack(unsigned ep, float v) {
  return ((unsigned long long)ep << 32) | (unsigned long long)__float_as_uint(v);
}
__device__ __forceinline__ unsigned long long packi(unsigned ep, int v) {
  return ((unsigned long long)ep << 32) | (unsigned long long)(unsigned)v;
}
__device__ __forceinline__ float val32(unsigned long long v) {
  return __uint_as_float((unsigned)v);
}
__device__ __forceinline__ int epok(unsigned long long v, unsigned ep) {
  return (unsigned)(v >> 32) == ep;
}

// ---- VT[p][i] = W_embed[i][1024+p]  (compact one-hot columns) ----
__global__ __launch_bounds__(256) void rnnss_vt_kernel(const float* __restrict__ We,
                                                       float* __restrict__ VT) {
  int n = blockIdx.x * 256 + threadIdx.x;      // 0..16383
  int p = n >> 10, i = n & 1023;
  VT[n] = We[(size_t)i * CAT + EMB + p];
}

// ---- U[t][i] = sum_k seq[t][k] * W_embed[i][k] + b_embed[i] ----
__global__ __launch_bounds__(256) void rnnss_uprep(const float* __restrict__ X,
                                                   const float* __restrict__ W,
                                                   const float* __restrict__ be,
                                                   float* __restrict__ U) {
  __shared__ __align__(16) float As[32][68];
  __shared__ __align__(16) float Bs[32][68];
  const int bm = blockIdx.x * 64;
  const int bn = blockIdx.y * 64;
  const int tid = threadIdx.x;
  const int tx = tid & 15, ty = tid >> 4;
  const int lr = tid >> 5, lc = tid & 31;
  float acc[4][4] = {};
  for (int k0 = 0; k0 < EMB; k0 += 32) {
#pragma unroll
    for (int p = 0; p < 8; ++p) {
      As[lc][lr + 8 * p] = X[(size_t)(bm + lr + 8 * p) * EMB + k0 + lc];
      Bs[lc][lr + 8 * p] = W[(size_t)(bn + lr + 8 * p) * CAT + k0 + lc];
    }
    __syncthreads();
#pragma unroll 8
    for (int k = 0; k < 32; ++k) {
      const float4 a = *(const float4*)&As[k][ty * 4];
      const float4 v = *(const float4*)&Bs[k][tx * 4];
      float am[4] = {a.x, a.y, a.z, a.w};
      float bv[4] = {v.x, v.y, v.z, v.w};
#pragma unroll
      for (int m = 0; m < 4; ++m)
#pragma unroll
        for (int n = 0; n < 4; ++n) acc[m][n] = fmaf(am[m], bv[n], acc[m][n]);
    }
    __syncthreads();
  }
#pragma unroll
  for (int m = 0; m < 4; ++m)
#pragma unroll
    for (int n = 0; n < 4; ++n)
      U[(size_t)(bm + ty * 4 + m) * EMB + bn + tx * 4 + n] =
          acc[m][n] + be[bn + tx * 4 + n];
}

// ---- persistent LSTM labeler: 256 blocks x 1024 threads ----
// Sync A (h broadcast): R14-proven stamped fused detect+gather (all blocks
//   need all of h -- true broadcast, 16KB/block atomic reads).
// Sync B (tag reduce) -- NEW leader design: only block 0 consumes tp.
//   All blocks post 16 stamped tp words (strided lines, parallel). Block 0
//   gathers 4096 words (32KB -- ONE block's worth instead of 256x = 8MB),
//   reduces (identical wave-tree order -> bit-identical stv), argmaxes, and
//   posts ONE stamped [ep|pred] word. Non-leaders: post tp -> Whh overlap ->
//   wave 0 spins the pred word (same-address reads merge at MALL; R6:
//   stores serialize, reads merge) -> LDS broadcast.
// Deadlock safety (one-step-lag, flag-free): pred(t) certifies b0 gathered
//   all tp(t); each block posts tp(t) only after finishing hpay(t) reads ->
//   hpay(t+1)/tp(t+1) overwrites are gated. pred slot: exact-epoch stamp.
// Weight residency unchanged; <=10 regs slack -- no new carried registers.
__global__ __launch_bounds__(NTHR, 4) void rnnss_persist(
    const float* __restrict__ Wih, const float* __restrict__ Whh,
    const float* __restrict__ bih, const float* __restrict__ bhh,
    const float* __restrict__ Witm, const float* __restrict__ bitm,
    const float* __restrict__ Wtag, const float* __restrict__ btag,
    const float* __restrict__ U, const float* __restrict__ VT,
    unsigned long long* __restrict__ hpay,  // [2048] stamped h, zeroed each call
    unsigned long long* __restrict__ tp64,  // [16][256] stamped tp, zeroed
    unsigned long long* __restrict__ predw, // [16] (slot 0 used), zeroed
    float* __restrict__ out) {
  __shared__ __align__(16) float sWi[32 * 1024];  // 128 KB: this block's W_ih rows
  __shared__ __align__(16) float se[EMB];
  __shared__ __align__(16) float sh[HID];
  __shared__ float sacc1[NTHR];  // carried Whh@h partial (per-thread slot)
  __shared__ float sg[32];     // gate preacts for this block's 8 units
  __shared__ float wpart[16];  // per-wave partials (phase B)
  __shared__ float stv[TAG];   // reduced tag scores (block 0 only)
  __shared__ float sc[8];      // persistent cell state (block-owned units)
  __shared__ int spred;        // broadcast pred (non-leaders)

  const int tid = threadIdx.x;
  const int b = blockIdx.x;
  const int u0 = b * 8;                 // hidden units [u0, u0+8)
  if (tid < 8) sc[tid] = 0.0f;
  sh[tid] = 0.0f;                       // initial carry h_0 = 0
  sh[tid + 1024] = 0.0f;
  sacc1[tid] = 0.0f;                    // Whh @ h_0 = 0

  // phase A row task: 32 gate rows x 32 lanes
  const int rt = tid >> 5;              // 0..31 : gsec*8 + j
  const int q = tid & 31;
  const int gsec = rt >> 3, j = rt & 7;
  const int grow = gsec * HID + u0 + j;
  const float bsum = bih[grow] + bhh[grow];
  const float4* __restrict__ wh = (const float4*)(Whh + (size_t)grow * HID);

  // phase B row task: 4 interm rows x 256 lanes
  const int brow = tid >> 8, bq = tid & 255;
  const float4* __restrict__ wm = (const float4*)(Witm + (size_t)(b * 4 + brow) * HID);
  float bi0 = 0, bi1 = 0, bi2 = 0, bi3 = 0;
  float wt0 = 0, wt1 = 0, wt2 = 0, wt3 = 0;
  if (tid < TAG) {
    bi0 = bitm[b * 4 + 0];
    bi1 = bitm[b * 4 + 1];
    bi2 = bitm[b * 4 + 2];
    bi3 = bitm[b * 4 + 3];
    wt0 = Wtag[(size_t)tid * 1024 + b * 4 + 0];
    wt1 = Wtag[(size_t)tid * 1024 + b * 4 + 1];
    wt2 = Wtag[(size_t)tid * 1024 + b * 4 + 2];
    wt3 = Wtag[(size_t)tid * 1024 + b * 4 + 3];
  }
  float btw = 0.0f;
  if ((tid & 63) == 0) btw = btag[tid >> 6];

  // ---- prologue: W_ih slice -> LDS (coalesced float4) ----
  {
    const float4* WiF = (const float4*)Wih;
    float4* sWiF = (float4*)sWi;
#pragma unroll
    for (int n = 0; n < 8; ++n) {
      int idx = tid + 1024 * n;          // 0..8191 float4s
      int r = idx >> 8, c = idx & 255;
      int gr = (r >> 3) * HID + u0 + (r & 7);
      sWiF[idx] = WiF[(size_t)gr * 256 + c];
    }
  }

  // ---- prologue: W_hh + W_interm slices -> registers, PINNED ----
  float4 rwh[16], rwm[2];
#pragma unroll
  for (int it = 0; it < 16; ++it) rwh[it] = wh[q + 32 * it];
  rwm[0] = wm[bq];
  rwm[1] = wm[bq + 256];
#pragma unroll
  for (int it = 0; it < 16; ++it)
    asm volatile("" : "+v"(rwh[it].x), "+v"(rwh[it].y), "+v"(rwh[it].z), "+v"(rwh[it].w));
  asm volatile("" : "+v"(rwm[0].x), "+v"(rwm[0].y), "+v"(rwm[0].z), "+v"(rwm[0].w));
  asm volatile("" : "+v"(rwm[1].x), "+v"(rwm[1].y), "+v"(rwm[1].z), "+v"(rwm[1].w));

  const float4* sef = (const float4*)se;
  const float4* shf = (const float4*)sh;
  const float4* sWiF4 = (const float4*)sWi;

  int pred = 0;               // __START__
  float u_cur = U[tid];       // U[0] prefetched
  __syncthreads();            // sWi / sc / sh / sacc1 ready

  for (int t = 0; t < T_STEPS; ++t) {
    const unsigned ep = (unsigned)t + 1u;

    // ---- phase A: e from prefetched U + VT[pred]; Wih@e + carried Whh@h ----
    {
      float ev = u_cur + VT[(size_t)pred * EMB + tid];
      se[tid] = ev > 0.0f ? ev : 0.0f;
    }
    __syncthreads();                                  // (1) se ready
    float acc0 = 0.0f;
#pragma unroll
    for (int it = 0; it < 8; ++it) {   // e part: 1024 (weights from LDS)
      float4 w = sWiF4[rt * 256 + q + 32 * it], x = sef[q + 32 * it];
      acc0 += w.x * x.x + w.y * x.y + w.z * x.z + w.w * x.w;
    }
    float acc = acc0 + sacc1[tid];     // + Whh@h_{t-1} (overlap of step t-1)
#pragma unroll
    for (int d = 16; d > 0; d >>= 1) acc += __shfl_down(acc, d, 32);
    if (q == 0) sg[rt] = acc + bsum;
    __syncthreads();                                  // (2) sg ready
    if (tid < 8) {                      // wave 0: LSTM pointwise + stamped h out
      float iv = sigf(sg[tid]);
      float fv = sigf(sg[8 + tid]);
      float gv = tanhf(sg[16 + tid]);
      float ov = sigf(sg[24 + tid]);
      float c = fv * sc[tid] + iv * gv;
      sc[tid] = c;
      // 8 lanes x 8B contiguous = 1 txn to block b's own 64B; no drain, no flag
      astore64(hpay + u0 + tid, pack(ep, ov * tanhf(c)));
    }

    // prefetch U[t+1] BEFORE the spin: issue under the sync-A detect window
    float u_nxt = (t + 1 < T_STEPS) ? U[(size_t)(t + 1) * EMB + tid] : 0.0f;

    // ---- sync A fused: stamped verify-gather of h_t (all 1024 threads) ----
    {
      const int lane = tid & 63;
      const int base = (tid >> 6) * 128 + lane;       // word indices base, base+64
      const unsigned long long* hp = hpay + base;
      unsigned long long v0 = aload64(hp);
      unsigned long long v1 = aload64(hp + 64);
      while (!epok(v0, ep)) { __builtin_amdgcn_s_sleep(1); v0 = aload64(hp); }
      while (!epok(v1, ep)) { __builtin_amdgcn_s_sleep(1); v1 = aload64(hp + 64); }
      sh[base] = val32(v0);
      sh[base + 64] = val32(v1);
    }
    __syncthreads();                                  // (3) sh = h_t ready

    // ---- phase B: interm partials + stamped tag partials ----
    {
      float a2 = 0.0f;
      float4 w = rwm[0], x = shf[bq];
      a2 += w.x * x.x + w.y * x.y + w.z * x.z + w.w * x.w;
      w = rwm[1]; x = shf[bq + 256];
      a2 += w.x * x.x + w.y * x.y + w.z * x.z + w.w * x.w;
#pragma unroll
      for (int d = 32; d > 0; d >>= 1) a2 += __shfl_down(a2, d, 64);
      if ((tid & 63) == 0) wpart[tid >> 6] = a2;
    }
    __syncthreads();                                  // (4) wpart ready
    if (tid < TAG) {                    // wave 0: finish interm + stamped tp out
      float i0 = wpart[0] + wpart[1] + wpart[2] + wpart[3] + bi0;
      float i1 = wpart[4] + wpart[5] + wpart[6] + wpart[7] + bi1;
      float i2 = wpart[8] + wpart[9] + wpart[10] + wpart[11] + bi2;
      float i3 = wpart[12] + wpart[13] + wpart[14] + wpart[15] + bi3;
      i0 = i0 > 0.0f ? i0 : 0.0f;
      i1 = i1 > 0.0f ? i1 : 0.0f;
      i2 = i2 > 0.0f ? i2 : 0.0f;
      i3 = i3 > 0.0f ? i3 : 0.0f;
      // 16 lanes -> 16 DIFFERENT 2KB-strided lines: parallel at MALL
      astore64(tp64 + tid * NBLK + b,
               pack(ep, wt0 * i0 + wt1 * i1 + wt2 * i2 + wt3 * i3));
    }

    int am = 0;
    if (b == 0) {
      // ---- leader: gather ALL tp (32KB, one block only), reduce, post pred
      {
        const int w = tid >> 6, l = tid & 63;  // 16 waves == 16 tags
        const unsigned long long* tp = tp64 + w * NBLK;
        unsigned long long p0 = aload64(tp + l);
        unsigned long long p1 = aload64(tp + 64 + l);
        unsigned long long p2 = aload64(tp + 128 + l);
        unsigned long long p3 = aload64(tp + 192 + l);
        while (!epok(p0, ep)) { __builtin_amdgcn_s_sleep(1); p0 = aload64(tp + l); }
        while (!epok(p1, ep)) { __builtin_amdgcn_s_sleep(1); p1 = aload64(tp + 64 + l); }
        while (!epok(p2, ep)) { __builtin_amdgcn_s_sleep(1); p2 = aload64(tp + 128 + l); }
        while (!epok(p3, ep)) { __builtin_amdgcn_s_sleep(1); p3 = aload64(tp + 192 + l); }
        float v = val32(p0) + val32(p1) + val32(p2) + val32(p3);
#pragma unroll
        for (int d = 32; d > 0; d >>= 1) v += __shfl_down(v, d, 64);
        if (l == 0) stv[w] = v + btw;
      }
      __syncthreads();                  // stv ready (block 0 only)
      {
        float bv = stv[0];
#pragma unroll
        for (int k = 1; k < TAG; ++k) {
          if (stv[k] > bv) { bv = stv[k]; am = k; }
        }
        if (tid == 0) astore64(predw, packi(ep, am));  // ONE word broadcast
      }
    }

    // ---- OVERLAP: Whh @ h_t for step t+1 -> LDS slot (all blocks) ----
    // Non-leaders: covers pred flight. Leader: after pred post (flight
    // overlaps its Whh + softmax).
    {
      float a1 = 0.0f;
#pragma unroll
      for (int it = 0; it < 16; ++it) {  // h part: 2048 (weights from VGPRs)
        float4 w = rwh[it], x = shf[q + 32 * it];
        a1 += w.x * x.x + w.y * x.y + w.z * x.z + w.w * x.w;
      }
      sacc1[tid] = a1;
    }

    if (b == 0) {
      pred = am;
      if (tid < TAG) {        // the only softmax computed on the whole chip
        float m = stv[0];
#pragma unroll
        for (int k = 1; k < TAG; ++k) m = fmaxf(m, stv[k]);
        float s = expf(stv[tid] - m);
#pragma unroll
        for (int msk = 8; msk > 0; msk >>= 1) s += __shfl_xor(s, msk, 16);
        float ls = logf(s);
        float lp = stv[tid] - m - ls;
        out[OUT_LOGP + t * TAG + tid] = lp;       // fire-and-forget stores
        out[OUT_PROB + t * TAG + tid] = expf(lp);
      } else if (tid == TAG) {
        out[OUT_PRED + t] = (float)am;
      }
      __syncthreads();                  // uniform with non-leader barrier count
    } else {
      // ---- spin ONE stamped pred word (wave 0), LDS-broadcast ----
      if (tid < 64) {
        unsigned long long pv = aload64(predw);   // same addr: 1 txn/wave; reads merge
        while (!epok(pv, ep)) { __builtin_amdgcn_s_sleep(1); pv = aload64(predw); }
        if (tid == 0) spred = (int)(unsigned)pv;
      }
      __syncthreads();                  // spred ready
      pred = spred;
    }
    u_cur = u_nxt;
    // no trailing sync: se/wpart next written behind >=1 sync of t+1
  }
}

extern "C" void kernel_launch(void* const* d_in, const int* in_sizes, int n_in,
                              void* d_out, int out_size, void* d_ws, size_t ws_size,
                              hipStream_t stream) {
  const float* seq = (const float*)d_in[0];
  const float* W_embed = (const float*)d_in[1];
  const float* b_embed = (const float*)d_in[2];
  const float* W_ih = (const float*)d_in[3];
  const float* W_hh = (const float*)d_in[4];
  const float* b_ih = (const float*)d_in[5];
  const float* b_hh = (const float*)d_in[6];
  const float* W_interm = (const float*)d_in[7];
  const float* b_interm = (const float*)d_in[8];
  const float* W_tag = (const float*)d_in[9];
  const float* b_tag = (const float*)d_in[10];
  (void)in_sizes; (void)n_in; (void)out_size; (void)ws_size;

  // ws layout: [hpay 16K][tp64 32K][predw 128B pad->4K][VT 64K][U 16M]
  const size_t hp_b = (size_t)HID * 8;
  const size_t tp_b = (size_t)TAG * NBLK * 8;
  const size_t pr_b = 4096;
  const size_t vt_b = (size_t)TAG * EMB * 4;

  char* ws = (char*)d_ws;
  unsigned long long* hpay = (unsigned long long*)ws;
  unsigned long long* tp64 = (unsigned long long*)(ws + hp_b);
  unsigned long long* predw = (unsigned long long*)(ws + hp_b + tp_b);
  float* VT = (float*)(ws + hp_b + tp_b + pr_b);
  float* U = (float*)(ws + hp_b + tp_b + pr_b + vt_b);
  float* out = (float*)d_out;

  // stamped buffers carry epoch state -> reset each call (graph replay safe;
  // epoch 0 matches no step's epoch 1..4096)
  hipMemsetAsync(ws, 0, hp_b + tp_b + pr_b, stream);

  hipLaunchKernelGGL(rnnss_vt_kernel, dim3((TAG * EMB) / 256), dim3(256), 0, stream,
                     W_embed, VT);
  hipLaunchKernelGGL(rnnss_uprep, dim3(T_STEPS / 64, EMB / 64), dim3(256), 0, stream,
                     seq, W_embed, b_embed, U);

  void* args[] = {
      (void*)&W_ih,    (void*)&W_hh,  (void*)&b_ih,  (void*)&b_hh,
      (void*)&W_interm,(void*)&b_interm, (void*)&W_tag, (void*)&b_tag,
      (void*)&U,       (void*)&VT,    (void*)&hpay,  (void*)&tp64,
      (void*)&predw,   (void*)&out};
  hipLaunchCooperativeKernel((const void*)rnnss_persist, dim3(NBLK), dim3(NTHR),
                             args, 0, stream);
}

// Round 16
// 28327.917 us; speedup vs baseline: 1.3083x; 1.3083x over previous
//
#include <hip/hip_runtime.h>
#include <math.h>

#define T_STEPS 4096
#define EMB 1024
#define HID 2048
#define CAT 1040
#define TAG 16
#define NBLK 256
#define NTHR 1024

// output offsets (floats)
#define OUT_LOGP 0
#define OUT_PROB (T_STEPS * TAG)
#define OUT_PRED (2 * T_STEPS * TAG)

__device__ __forceinline__ float sigf(float x) { return 1.0f / (1.0f + expf(-x)); }

// epoch-stamped 64-bit payload: [epoch:32 | f32:32]; value+freshness one atom.
// Relaxed agent-scope -> serviced at the coherent point; no fences anywhere.
__device__ __forceinline__ unsigned long long aload64(const unsigned long long* p) {
  return __hip_atomic_load(p, __ATOMIC_RELAXED, __HIP_MEMORY_SCOPE_AGENT);
}
__device__ __forceinline__ void astore64(unsigned long long* p, unsigned long long v) {
  __hip_atomic_store(p, v, __ATOMIC_RELAXED, __HIP_MEMORY_SCOPE_AGENT);
}
__device__ __forceinline__ unsigned long long pack(unsigned ep, float v) {
  return ((unsigned long long)ep << 32) | (unsigned long long)__float_as_uint(v);
}
__device__ __forceinline__ float val32(unsigned long long v) {
  return __uint_as_float((unsigned)v);
}
__device__ __forceinline__ int epok(unsigned long long v, unsigned ep) {
  return (unsigned)(v >> 32) == ep;
}

// ---- VT[p][i] = W_embed[i][1024+p]  (compact one-hot columns) ----
__global__ __launch_bounds__(256) void rnnss_vt_kernel(const float* __restrict__ We,
                                                       float* __restrict__ VT) {
  int n = blockIdx.x * 256 + threadIdx.x;      // 0..16383
  int p = n >> 10, i = n & 1023;
  VT[n] = We[(size_t)i * CAT + EMB + p];
}

// ---- U[t][i] = sum_k seq[t][k] * W_embed[i][k] + b_embed[i] ----
__global__ __launch_bounds__(256) void rnnss_uprep(const float* __restrict__ X,
                                                   const float* __restrict__ W,
                                                   const float* __restrict__ be,
                                                   float* __restrict__ U) {
  __shared__ __align__(16) float As[32][68];
  __shared__ __align__(16) float Bs[32][68];
  const int bm = blockIdx.x * 64;
  const int bn = blockIdx.y * 64;
  const int tid = threadIdx.x;
  const int tx = tid & 15, ty = tid >> 4;
  const int lr = tid >> 5, lc = tid & 31;
  float acc[4][4] = {};
  for (int k0 = 0; k0 < EMB; k0 += 32) {
#pragma unroll
    for (int p = 0; p < 8; ++p) {
      As[lc][lr + 8 * p] = X[(size_t)(bm + lr + 8 * p) * EMB + k0 + lc];
      Bs[lc][lr + 8 * p] = W[(size_t)(bn + lr + 8 * p) * CAT + k0 + lc];
    }
    __syncthreads();
#pragma unroll 8
    for (int k = 0; k < 32; ++k) {
      const float4 a = *(const float4*)&As[k][ty * 4];
      const float4 v = *(const float4*)&Bs[k][tx * 4];
      float am[4] = {a.x, a.y, a.z, a.w};
      float bv[4] = {v.x, v.y, v.z, v.w};
#pragma unroll
      for (int m = 0; m < 4; ++m)
#pragma unroll
        for (int n = 0; n < 4; ++n) acc[m][n] = fmaf(am[m], bv[n], acc[m][n]);
    }
    __syncthreads();
  }
#pragma unroll
  for (int m = 0; m < 4; ++m)
#pragma unroll
    for (int n = 0; n < 4; ++n)
      U[(size_t)(bm + ty * 4 + m) * EMB + bn + tx * 4 + n] =
          acc[m][n] + be[bn + tx * 4 + n];
}

// ---- persistent LSTM labeler: 256 blocks x 1024 threads ----
// BOTH cross-block exchanges are epoch-stamped fused detect+gathers: NO
// flags, NO drains, NO grid barriers anywhere (R14-proven, 28.86 ms).
//   hpay[u]     : [ep|h_u]  -- 8 u64/block, 64B contiguous
//   tp64[g][b]  : [ep|tp]   -- 16 lanes -> 16 distinct 2KB-strided lines
// Consumers issue coalesced stamped loads FIRST, then retry only stale
// words (8B each) -- bounded retry traffic. Symmetric all-gather on both
// exchanges: hop depth 1 (R15 proved leader/relay designs add serial hops
// that cost far more than redundant merged reads, which are free).
// Deadlock-safety (one-step-lag induction, flag-free): b overwrites hpay at
// t+1 only after gathering all tp(t); r posts tp(t) only after finishing all
// hpay(t) reads -> hpay(t) readers done before overwrite. Symmetrically for
// tp overwrites vs hpay(t+1) gathers.
// Whh@h_t overlap (R12-proven): computed between tp post and tp gather, in
// the LDS slot sacc1[tid] (NOT a register -- <=10 regs slack; R10 spill).
__global__ __launch_bounds__(NTHR, 4) void rnnss_persist(
    const float* __restrict__ Wih, const float* __restrict__ Whh,
    const float* __restrict__ bih, const float* __restrict__ bhh,
    const float* __restrict__ Witm, const float* __restrict__ bitm,
    const float* __restrict__ Wtag, const float* __restrict__ btag,
    const float* __restrict__ U, const float* __restrict__ VT,
    unsigned long long* __restrict__ hpay,  // [2048] stamped h, zeroed each call
    unsigned long long* __restrict__ tp64,  // [16][256] stamped tp, zeroed
    float* __restrict__ out) {
  __shared__ __align__(16) float sWi[32 * 1024];  // 128 KB: this block's W_ih rows
  __shared__ __align__(16) float se[EMB];
  __shared__ __align__(16) float sh[HID];
  __shared__ float sacc1[NTHR];  // carried Whh@h partial (per-thread slot)
  __shared__ float sg[32];     // gate preacts for this block's 8 units
  __shared__ float wpart[16];  // per-wave partials (phase B)
  __shared__ float stv[TAG];   // reduced tag scores
  __shared__ float sc[8];      // persistent cell state (block-owned units)

  const int tid = threadIdx.x;
  const int b = blockIdx.x;
  const int u0 = b * 8;                 // hidden units [u0, u0+8)
  if (tid < 8) sc[tid] = 0.0f;
  sh[tid] = 0.0f;                       // initial carry h_0 = 0
  sh[tid + 1024] = 0.0f;
  sacc1[tid] = 0.0f;                    // Whh @ h_0 = 0

  // phase A row task: 32 gate rows x 32 lanes
  const int rt = tid >> 5;              // 0..31 : gsec*8 + j
  const int q = tid & 31;
  const int gsec = rt >> 3, j = rt & 7;
  const int grow = gsec * HID + u0 + j;
  const float bsum = bih[grow] + bhh[grow];
  const float4* __restrict__ wh = (const float4*)(Whh + (size_t)grow * HID);

  // phase B row task: 4 interm rows x 256 lanes
  const int brow = tid >> 8, bq = tid & 255;
  const float4* __restrict__ wm = (const float4*)(Witm + (size_t)(b * 4 + brow) * HID);
  float bi0 = 0, bi1 = 0, bi2 = 0, bi3 = 0;
  float wt0 = 0, wt1 = 0, wt2 = 0, wt3 = 0;
  if (tid < TAG) {
    bi0 = bitm[b * 4 + 0];
    bi1 = bitm[b * 4 + 1];
    bi2 = bitm[b * 4 + 2];
    bi3 = bitm[b * 4 + 3];
    wt0 = Wtag[(size_t)tid * 1024 + b * 4 + 0];
    wt1 = Wtag[(size_t)tid * 1024 + b * 4 + 1];
    wt2 = Wtag[(size_t)tid * 1024 + b * 4 + 2];
    wt3 = Wtag[(size_t)tid * 1024 + b * 4 + 3];
  }
  float btw = 0.0f;
  if ((tid & 63) == 0) btw = btag[tid >> 6];

  // ---- prologue: W_ih slice -> LDS (coalesced float4) ----
  {
    const float4* WiF = (const float4*)Wih;
    float4* sWiF = (float4*)sWi;
#pragma unroll
    for (int n = 0; n < 8; ++n) {
      int idx = tid + 1024 * n;          // 0..8191 float4s
      int r = idx >> 8, c = idx & 255;
      int gr = (r >> 3) * HID + u0 + (r & 7);
      sWiF[idx] = WiF[(size_t)gr * 256 + c];
    }
  }

  // ---- prologue: W_hh + W_interm slices -> registers, PINNED ----
  float4 rwh[16], rwm[2];
#pragma unroll
  for (int it = 0; it < 16; ++it) rwh[it] = wh[q + 32 * it];
  rwm[0] = wm[bq];
  rwm[1] = wm[bq + 256];
#pragma unroll
  for (int it = 0; it < 16; ++it)
    asm volatile("" : "+v"(rwh[it].x), "+v"(rwh[it].y), "+v"(rwh[it].z), "+v"(rwh[it].w));
  asm volatile("" : "+v"(rwm[0].x), "+v"(rwm[0].y), "+v"(rwm[0].z), "+v"(rwm[0].w));
  asm volatile("" : "+v"(rwm[1].x), "+v"(rwm[1].y), "+v"(rwm[1].z), "+v"(rwm[1].w));

  const float4* sef = (const float4*)se;
  const float4* shf = (const float4*)sh;
  const float4* sWiF4 = (const float4*)sWi;

  int pred = 0;               // __START__
  float u_cur = U[tid];       // U[0] prefetched
  __syncthreads();            // sWi / sc / sh / sacc1 ready

  for (int t = 0; t < T_STEPS; ++t) {
    const unsigned ep = (unsigned)t + 1u;

    // ---- phase A: e from prefetched U + VT[pred]; Wih@e + carried Whh@h ----
    {
      float ev = u_cur + VT[(size_t)pred * EMB + tid];
      se[tid] = ev > 0.0f ? ev : 0.0f;
    }
    __syncthreads();                                  // (1) se ready
    float acc0 = 0.0f;
#pragma unroll
    for (int it = 0; it < 8; ++it) {   // e part: 1024 (weights from LDS)
      float4 w = sWiF4[rt * 256 + q + 32 * it], x = sef[q + 32 * it];
      acc0 += w.x * x.x + w.y * x.y + w.z * x.z + w.w * x.w;
    }
    float acc = acc0 + sacc1[tid];     // + Whh@h_{t-1} (overlap of step t-1)
#pragma unroll
    for (int d = 16; d > 0; d >>= 1) acc += __shfl_down(acc, d, 32);
    if (q == 0) sg[rt] = acc + bsum;
    __syncthreads();                                  // (2) sg ready
    if (tid < 8) {                      // wave 0: LSTM pointwise + stamped h out
      float iv = sigf(sg[tid]);
      float fv = sigf(sg[8 + tid]);
      float gv = tanhf(sg[16 + tid]);
      float ov = sigf(sg[24 + tid]);
      float c = fv * sc[tid] + iv * gv;
      sc[tid] = c;
      // 8 lanes x 8B contiguous = 1 txn to block b's own 64B; no drain, no flag
      astore64(hpay + u0 + tid, pack(ep, ov * tanhf(c)));
    }

    // prefetch U[t+1] BEFORE the spin: issue under the sync-A detect window
    float u_nxt = (t + 1 < T_STEPS) ? U[(size_t)(t + 1) * EMB + tid] : 0.0f;

    // ---- sync A fused: stamped verify-gather of h_t (all 1024 threads) ----
    {
      const int lane = tid & 63;
      const int base = (tid >> 6) * 128 + lane;       // word indices base, base+64
      const unsigned long long* hp = hpay + base;
      unsigned long long v0 = aload64(hp);
      unsigned long long v1 = aload64(hp + 64);
      while (!epok(v0, ep)) { __builtin_amdgcn_s_sleep(1); v0 = aload64(hp); }
      while (!epok(v1, ep)) { __builtin_amdgcn_s_sleep(1); v1 = aload64(hp + 64); }
      sh[base] = val32(v0);
      sh[base + 64] = val32(v1);
    }
    __syncthreads();                                  // (3) sh = h_t ready

    // ---- phase B: interm partials + stamped tag partials ----
    {
      float a2 = 0.0f;
      float4 w = rwm[0], x = shf[bq];
      a2 += w.x * x.x + w.y * x.y + w.z * x.z + w.w * x.w;
      w = rwm[1]; x = shf[bq + 256];
      a2 += w.x * x.x + w.y * x.y + w.z * x.z + w.w * x.w;
#pragma unroll
      for (int d = 32; d > 0; d >>= 1) a2 += __shfl_down(a2, d, 64);
      if ((tid & 63) == 0) wpart[tid >> 6] = a2;
    }
    __syncthreads();                                  // (4) wpart ready
    if (tid < TAG) {                    // wave 0: finish interm + stamped tp out
      float i0 = wpart[0] + wpart[1] + wpart[2] + wpart[3] + bi0;
      float i1 = wpart[4] + wpart[5] + wpart[6] + wpart[7] + bi1;
      float i2 = wpart[8] + wpart[9] + wpart[10] + wpart[11] + bi2;
      float i3 = wpart[12] + wpart[13] + wpart[14] + wpart[15] + bi3;
      i0 = i0 > 0.0f ? i0 : 0.0f;
      i1 = i1 > 0.0f ? i1 : 0.0f;
      i2 = i2 > 0.0f ? i2 : 0.0f;
      i3 = i3 > 0.0f ? i3 : 0.0f;
      // 16 lanes -> 16 DIFFERENT 2KB-strided lines: parallel at MALL
      astore64(tp64 + tid * NBLK + b,
               pack(ep, wt0 * i0 + wt1 * i1 + wt2 * i2 + wt3 * i3));
    }

    // ---- OVERLAP (sync-B window): Whh @ h_t for step t+1 -> LDS slot ----
    {
      float a1 = 0.0f;
#pragma unroll
      for (int it = 0; it < 16; ++it) {  // h part: 2048 (weights from VGPRs)
        float4 w = rwh[it], x = shf[q + 32 * it];
        a1 += w.x * x.x + w.y * x.y + w.z * x.z + w.w * x.w;
      }
      sacc1[tid] = a1;
    }

    // ---- sync B fused: stamped verify-gather of tag partials + reduce ----
    {
      const int w = tid >> 6, l = tid & 63;  // 16 waves == 16 tags
      const unsigned long long* tp = tp64 + w * NBLK;
      unsigned long long p0 = aload64(tp + l);
      unsigned long long p1 = aload64(tp + 64 + l);
      unsigned long long p2 = aload64(tp + 128 + l);
      unsigned long long p3 = aload64(tp + 192 + l);
      while (!epok(p0, ep)) { __builtin_amdgcn_s_sleep(1); p0 = aload64(tp + l); }
      while (!epok(p1, ep)) { __builtin_amdgcn_s_sleep(1); p1 = aload64(tp + 64 + l); }
      while (!epok(p2, ep)) { __builtin_amdgcn_s_sleep(1); p2 = aload64(tp + 128 + l); }
      while (!epok(p3, ep)) { __builtin_amdgcn_s_sleep(1); p3 = aload64(tp + 192 + l); }
      float v = val32(p0) + val32(p1) + val32(p2) + val32(p3);
#pragma unroll
      for (int d = 32; d > 0; d >>= 1) v += __shfl_down(v, d, 64);
      if (l == 0) stv[w] = v + btw;
    }
    __syncthreads();                                  // (5) stv ready

    // ---- phase C: argmax everywhere; softmax only on block 0 ----
    {
      int am = 0;
      float bv = stv[0];
#pragma unroll
      for (int k = 1; k < TAG; ++k) {
        if (stv[k] > bv) { bv = stv[k]; am = k; }
      }
      pred = am;
      if (b == 0) {
        if (tid < TAG) {      // lanes 0-15 of wave 0: the only softmax computed
          float m = stv[0];
#pragma unroll
          for (int k = 1; k < TAG; ++k) m = fmaxf(m, stv[k]);
          float s = expf(stv[tid] - m);
#pragma unroll
          for (int msk = 8; msk > 0; msk >>= 1) s += __shfl_xor(s, msk, 16);
          float ls = logf(s);
          float lp = stv[tid] - m - ls;
          out[OUT_LOGP + t * TAG + tid] = lp;
          out[OUT_PROB + t * TAG + tid] = expf(lp);
        } else if (tid == TAG) {
          out[OUT_PRED + t] = (float)am;
        }
      }
      u_cur = u_nxt;
      // no trailing sync: stv/wpart/se next written behind >=1 sync of t+1
    }
  }
}

extern "C" void kernel_launch(void* const* d_in, const int* in_sizes, int n_in,
                              void* d_out, int out_size, void* d_ws, size_t ws_size,
                              hipStream_t stream) {
  const float* seq = (const float*)d_in[0];
  const float* W_embed = (const float*)d_in[1];
  const float* b_embed = (const float*)d_in[2];
  const float* W_ih = (const float*)d_in[3];
  const float* W_hh = (const float*)d_in[4];
  const float* b_ih = (const float*)d_in[5];
  const float* b_hh = (const float*)d_in[6];
  const float* W_interm = (const float*)d_in[7];
  const float* b_interm = (const float*)d_in[8];
  const float* W_tag = (const float*)d_in[9];
  const float* b_tag = (const float*)d_in[10];
  (void)in_sizes; (void)n_in; (void)out_size; (void)ws_size;

  // ws layout: [hpay 16K][tp64 32K][VT 64K][U 16M]
  const size_t hp_b = (size_t)HID * 8;
  const size_t tp_b = (size_t)TAG * NBLK * 8;
  const size_t vt_b = (size_t)TAG * EMB * 4;

  char* ws = (char*)d_ws;
  unsigned long long* hpay = (unsigned long long*)ws;
  unsigned long long* tp64 = (unsigned long long*)(ws + hp_b);
  float* VT = (float*)(ws + hp_b + tp_b);
  float* U = (float*)(ws + hp_b + tp_b + vt_b);
  float* out = (float*)d_out;

  // stamped buffers carry epoch state -> reset each call (graph replay safe;
  // epoch 0 matches no step's epoch 1..4096)
  hipMemsetAsync(ws, 0, hp_b + tp_b, stream);

  hipLaunchKernelGGL(rnnss_vt_kernel, dim3((TAG * EMB) / 256), dim3(256), 0, stream,
                     W_embed, VT);
  hipLaunchKernelGGL(rnnss_uprep, dim3(T_STEPS / 64, EMB / 64), dim3(256), 0, stream,
                     seq, W_embed, b_embed, U);

  void* args[] = {
      (void*)&W_ih,    (void*)&W_hh,  (void*)&b_ih,  (void*)&b_hh,
      (void*)&W_interm,(void*)&b_interm, (void*)&W_tag, (void*)&b_tag,
      (void*)&U,       (void*)&VT,    (void*)&hpay,  (void*)&tp64,
      (void*)&out};
  hipLaunchCooperativeKernel((const void*)rnnss_persist, dim3(NBLK), dim3(NTHR),
                             args, 0, stream);
}